// Round 5
// baseline (270.058 us; speedup 1.0000x reference)
//
#include <hip/hip_runtime.h>
#include <stdint.h>

#define NM 16
#define HW_P 589824            // 768*768 pixels per mask
#define U8PM 9216              // 64-bit words per mask
#define F4PM 147456            // float4s per mask
#define F4PT 2359296           // float4s per tensor (16 masks)
#define PT 512                 // pipeline threads
#define NG 8                   // column groups (WGs), 2 cols each

typedef unsigned long long u64;
typedef float vf4 __attribute__((ext_vector_type(4)));

// meta ints: [32..47] flagsA | [48..63] flagsB | [64..71] cons (boundary g) |
// [96..207] prodflag[g*16+t] one-shot: bit0 valid | bits1..20 pca | bit21 fa

// spread 8 bits to every 4th bit of a 32-bit word
__device__ __forceinline__ uint32_t spread4(uint32_t x) {
    uint32_t t = (x | (x << 12)) & 0x000F000Fu;
    t = (t | (t << 6)) & 0x03030303u;
    t = (t | (t << 3)) & 0x11111111u;
    return t;
}

// ---------------- kernel 1: binarize (coalesced, NT loads, fused meta-zero) -
__global__ __launch_bounds__(256) void binarize_kernel(
    const float* __restrict__ ma, const float* __restrict__ mb,
    uint32_t* __restrict__ bitsA, uint32_t* __restrict__ bitsB,
    int* __restrict__ meta)
{
    if (blockIdx.x == 0) meta[threadIdx.x] = 0;    // pc/flags/cons/prodflag
    int g = blockIdx.x * 256 + threadIdx.x;        // float4 index
    int tensor = (g >= F4PT);                      // boundary %64==0: wave-uniform
    int lg = tensor ? (g - F4PT) : g;
    const float* src = tensor ? mb : ma;
    vf4 v = __builtin_nontemporal_load(((const vf4*)src) + lg);
    unsigned long long q0 = __ballot(v.x > 0.0f);
    unsigned long long q1 = __ballot(v.y > 0.0f);
    unsigned long long q2 = __ballot(v.z > 0.0f);
    unsigned long long q3 = __ballot(v.w > 0.0f);
    int lane = threadIdx.x & 63;
    if (lane < 8) {
        uint32_t wd = spread4((uint32_t)(q0 >> (8 * lane)) & 0xFFu)
                    | (spread4((uint32_t)(q1 >> (8 * lane)) & 0xFFu) << 1)
                    | (spread4((uint32_t)(q2 >> (8 * lane)) & 0xFFu) << 2)
                    | (spread4((uint32_t)(q3 >> (8 * lane)) & 0xFFu) << 3);
        uint32_t* bits = tensor ? bitsB : bitsA;
        bits[((lg & ~63) >> 3) + lane] = wd;       // word = 8 float4s
    }
}

// ---------------- kernel 2: systolic pipeline, 2 barriers/row --------------
// WG g owns columns 2g,2g+1 in registers. Row a_i flows g-1 -> g as 72 KB of
// agent-scope (sc1) 8-B atomics through L3; 4-deep slots + one-shot per-row
// flags. tid64/tid65 poll next row's flag / slot credit DURING this row's
// stores, so detect latency hides behind the store drain. Thread t owns u64
// pairs {2t+1024w, +1} so local loads/stores are plain dwordx4.
__global__ __launch_bounds__(PT, 1) void pipeline_kernel(
    const float* __restrict__ sa, const float* __restrict__ sb,
    uint32_t* bitsA, uint32_t* bitsB, int* meta, u64* msg)
{
    int* flagsA = meta + 32;
    int* flagsB = meta + 48;
    unsigned* cons = (unsigned*)(meta + 64);
    unsigned* prodflag = (unsigned*)(meta + 96);

    const int g = blockIdx.x;
    const int tid = threadIdx.x;
    const int wave = tid >> 6, lane = tid & 63;
    const int c0 = 2 * g, c1 = 2 * g + 1;

    __shared__ int part[8][4];
    __shared__ unsigned smeta_s;

    u64* A8 = (u64*)bitsA;
    u64* B8 = (u64*)bitsB;

    u64 a[18], b0[18], b1[18];

    // ---- load b columns (plain dwordx4; kernel boundary flushed) ----------
    const uint4* Bc0 = (const uint4*)(B8 + (size_t)c0 * U8PM);
    const uint4* Bc1 = (const uint4*)(B8 + (size_t)c1 * U8PM);
#pragma unroll
    for (int w = 0; w < 9; ++w) {
        uint4 q0 = Bc0[tid + PT * w];
        uint4 q1 = Bc1[tid + PT * w];
        b0[2 * w]     = ((u64)q0.y << 32) | q0.x;
        b0[2 * w + 1] = ((u64)q0.w << 32) | q0.z;
        b1[2 * w]     = ((u64)q1.y << 32) | q1.x;
        b1[2 * w + 1] = ((u64)q1.w << 32) | q1.z;
    }
    int v0 = 0, v1 = 0;
#pragma unroll
    for (int w = 0; w < 18; ++w) { v0 += __popcll(b0[w]); v1 += __popcll(b1[w]); }
#pragma unroll
    for (int off = 32; off >= 1; off >>= 1) {
        v0 += __shfl_xor(v0, off); v1 += __shfl_xor(v1, off);
    }
    if (lane == 0) { part[wave][0] = v0; part[wave][1] = v1; }
    __syncthreads();
    int pcb0 = 0, pcb1 = 0;
#pragma unroll
    for (int w = 0; w < 8; ++w) { pcb0 += part[wave ? 0 : 0][0], pcb0 = 0; break; }
    pcb0 = 0; pcb1 = 0;
#pragma unroll
    for (int w = 0; w < 8; ++w) { pcb0 += part[w][0]; pcb1 += part[w][1]; }
    // pre-loop: poll row 0's flag (overlaps nothing, once)
    if (g > 0 && tid == 64) {
        unsigned v;
        while (!(v = __hip_atomic_load(&prodflag[(g - 1) * 16 + 0],
                                       __ATOMIC_RELAXED, __HIP_MEMORY_SCOPE_AGENT))) {}
        smeta_s = v;
    }
    __syncthreads();          // part reuse + smeta visible
    unsigned mv = smeta_s;    // undefined for g==0, unused there

    float sb0 = sb[c0], sb1 = sb[c1];
    int fb0 = 0, fb1 = 0;

    for (int t = 0; t < NM; ++t) {
        int pca, fa;
        if (g == 0) { pca = 0; fa = 0; }
        else { pca = (int)((mv >> 1) & 0xFFFFFu); fa = (int)((mv >> 21) & 1u); }

        // ---- load row t -----------------------------------------------------
        if (g == 0) {
            const uint4* Ar = (const uint4*)(A8 + (size_t)t * U8PM);
#pragma unroll
            for (int w = 0; w < 9; ++w) {
                uint4 q = Ar[tid + PT * w];
                a[2 * w]     = ((u64)q.y << 32) | q.x;
                a[2 * w + 1] = ((u64)q.w << 32) | q.z;
            }
        } else {
            const u64* slot_in = msg + (size_t)((g - 1) * 4 + (t & 3)) * U8PM;
#pragma unroll
            for (int w = 0; w < 9; ++w) {
                int base = 2 * tid + 1024 * w;
                a[2 * w]     = __hip_atomic_load(&slot_in[base],
                                __ATOMIC_RELAXED, __HIP_MEMORY_SCOPE_AGENT);
                a[2 * w + 1] = __hip_atomic_load(&slot_in[base + 1],
                                __ATOMIC_RELAXED, __HIP_MEMORY_SCOPE_AGENT);
            }
        }

        // ---- fused popc terms ----------------------------------------------
        int i0 = 0, i1 = 0, itr = 0, ipc = 0;
#pragma unroll
        for (int w = 0; w < 18; ++w) {
            u64 ab0 = a[w] & b0[w];
            i0 += __popcll(ab0);
            i1 += __popcll(a[w] & b1[w]);
            itr += __popcll(ab0 & b1[w]);
        }
        if (g == 0) {
#pragma unroll
            for (int w = 0; w < 18; ++w) ipc += __popcll(a[w]);
        }
#pragma unroll
        for (int off = 32; off >= 1; off >>= 1) {
            i0 += __shfl_xor(i0, off); i1 += __shfl_xor(i1, off);
            itr += __shfl_xor(itr, off); ipc += __shfl_xor(ipc, off);
        }
        if (lane == 0) {
            part[wave][0] = i0; part[wave][1] = i1;
            part[wave][2] = itr; part[wave][3] = ipc;
        }
        __syncthreads();   // B2: partials visible, row loads retired
        if (g > 0 && tid == 67)   // loads of slot (t&3) retired -> credit
            __hip_atomic_store(&cons[g - 1], (unsigned)(t + 1),
                               __ATOMIC_RELAXED, __HIP_MEMORY_SCOPE_AGENT);
        int I0 = 0, I1 = 0, T = 0, PC = 0;
#pragma unroll
        for (int w = 0; w < 8; ++w) {
            I0 += part[w][0]; I1 += part[w][1];
            T  += part[w][2]; PC += part[w][3];
        }
        if (g == 0) pca = PC;

        float sai = sa[t];
        // ---- pair (t, c0): replicate reference fp32 arithmetic exactly ----
        bool aupd = false;
        {
            int inter = I0;
            int uni = pca + pcb0 - inter;
            float iou = (float)inter / fmaxf((float)uni, 1.0f);
            bool aw = sai > sb0;
            if (iou > 0.8f) { if (aw) fb0 = 1; else fa = 1; }
            else if (inter > 0) {
                if (aw) {
                    pcb0 -= inter;
#pragma unroll
                    for (int w = 0; w < 18; ++w) b0[w] &= ~a[w];
                } else {
                    pca -= inter; aupd = true;
#pragma unroll
                    for (int w = 0; w < 18; ++w) a[w] &= ~b0[w];
                }
            }
        }
        // ---- pair (t, c1): exact inter via speculative triple term --------
        {
            int inter = aupd ? (I1 - T) : I1;
            int uni = pca + pcb1 - inter;
            float iou = (float)inter / fmaxf((float)uni, 1.0f);
            bool aw = sai > sb1;
            if (iou > 0.8f) { if (aw) fb1 = 1; else fa = 1; }
            else if (inter > 0) {
                if (aw) {
                    pcb1 -= inter;
#pragma unroll
                    for (int w = 0; w < 18; ++w) b1[w] &= ~a[w];
                } else {
                    pca -= inter;
#pragma unroll
                    for (int w = 0; w < 18; ++w) a[w] &= ~b1[w];
                }
            }
        }

        // ---- forward / finalize row ----------------------------------------
        if (g < NG - 1) {
            u64* slot_out = msg + (size_t)(g * 4 + (t & 3)) * U8PM;
#pragma unroll
            for (int w = 0; w < 9; ++w) {
                int base = 2 * tid + 1024 * w;
                __hip_atomic_store(&slot_out[base], a[2 * w],
                                   __ATOMIC_RELAXED, __HIP_MEMORY_SCOPE_AGENT);
                __hip_atomic_store(&slot_out[base + 1], a[2 * w + 1],
                                   __ATOMIC_RELAXED, __HIP_MEMORY_SCOPE_AGENT);
            }
        } else {
            uint4* Ar = (uint4*)(A8 + (size_t)t * U8PM);
#pragma unroll
            for (int w = 0; w < 9; ++w) {
                uint4 q;
                q.x = (uint32_t)a[2 * w];     q.y = (uint32_t)(a[2 * w] >> 32);
                q.z = (uint32_t)a[2 * w + 1]; q.w = (uint32_t)(a[2 * w + 1] >> 32);
                Ar[tid + PT * w] = q;
            }
            if (tid == 0) flagsA[t] = fa;
        }

        // ---- overlapped polls for row t+1 (hide behind store drain) -------
        if (g > 0 && t + 1 < NM && tid == 64) {
            unsigned v;
            while (!(v = __hip_atomic_load(&prodflag[(g - 1) * 16 + t + 1],
                                           __ATOMIC_RELAXED, __HIP_MEMORY_SCOPE_AGENT))) {}
            smeta_s = v;
        }
        if (g < NG - 1 && t + 1 < NM && t + 1 >= 4 && tid == 65) {
            while (__hip_atomic_load(&cons[g], __ATOMIC_RELAXED,
                                     __HIP_MEMORY_SCOPE_AGENT) < (unsigned)(t - 2)) {}
        }
        __syncthreads();   // B3: stores drained at L3, polls done
        if (g < NG - 1 && tid == 0)
            __hip_atomic_store(&prodflag[g * 16 + t],
                               1u | ((unsigned)pca << 1) | ((unsigned)fa << 21),
                               __ATOMIC_RELAXED, __HIP_MEMORY_SCOPE_AGENT);
        mv = smeta_s;
    }

    // final b columns + flags; kernel-end flush publishes to expand_kernel
    uint4* Wc0 = (uint4*)(B8 + (size_t)c0 * U8PM);
    uint4* Wc1 = (uint4*)(B8 + (size_t)c1 * U8PM);
#pragma unroll
    for (int w = 0; w < 9; ++w) {
        uint4 q0, q1;
        q0.x = (uint32_t)b0[2 * w];     q0.y = (uint32_t)(b0[2 * w] >> 32);
        q0.z = (uint32_t)b0[2 * w + 1]; q0.w = (uint32_t)(b0[2 * w + 1] >> 32);
        q1.x = (uint32_t)b1[2 * w];     q1.y = (uint32_t)(b1[2 * w] >> 32);
        q1.z = (uint32_t)b1[2 * w + 1]; q1.w = (uint32_t)(b1[2 * w + 1] >> 32);
        Wc0[tid + PT * w] = q0;
        Wc1[tid + PT * w] = q1;
    }
    if (tid == 0) { flagsB[c0] = fb0; flagsB[c1] = fb1; }
}

// ---------------- kernel 3: expand (coalesced, NT stores) ------------------
__global__ __launch_bounds__(256) void expand_kernel(
    const uint32_t* __restrict__ bitsA, const uint32_t* __restrict__ bitsB,
    const int* __restrict__ meta, float* __restrict__ out)
{
    int g = blockIdx.x * 256 + threadIdx.x;        // float4 index
    int tensor = (g >= F4PT);
    int lg = tensor ? (g - F4PT) : g;
    const uint32_t* bits = tensor ? bitsB : bitsA;
    const int* flags = meta + (tensor ? 48 : 32);
    int m = lg / F4PM;
    bool keep = (flags[m] == 0);
    uint32_t wd = keep ? bits[lg >> 3] : 0u;
    int sh = (lg & 7) * 4;
    vf4 o;
    o.x = ((wd >> (sh + 0)) & 1u) ? 1.0f : 0.0f;
    o.y = ((wd >> (sh + 1)) & 1u) ? 1.0f : 0.0f;
    o.z = ((wd >> (sh + 2)) & 1u) ? 1.0f : 0.0f;
    o.w = ((wd >> (sh + 3)) & 1u) ? 1.0f : 0.0f;
    __builtin_nontemporal_store(o, ((vf4*)out) + g);
    if (g < 2 * NM) {   // keep_a / keep_b tail (flagsA,flagsB contiguous)
        const int* f = meta + 32;
        out[(size_t)2 * NM * HW_P + g] = f[g] ? 0.0f : 1.0f;
    }
}

extern "C" void kernel_launch(void* const* d_in, const int* in_sizes, int n_in,
                              void* d_out, int out_size, void* d_ws, size_t ws_size,
                              hipStream_t stream)
{
    const float* ma = (const float*)d_in[0];
    const float* mb = (const float*)d_in[1];
    const float* sa = (const float*)d_in[2];
    const float* sb = (const float*)d_in[3];
    float* out = (float*)d_out;
    char* ws = (char*)d_ws;

    uint32_t* bitsA = (uint32_t*)(ws);             // 1,179,648 B
    uint32_t* bitsB = (uint32_t*)(ws + 1179648);   // 1,179,648 B
    int* meta       = (int*)(ws + 2359296);        // 1024 B reserved
    u64* msg        = (u64*)(ws + 2360320);        // 28 slots * 73,728 B

    binarize_kernel<<<18432, 256, 0, stream>>>(ma, mb, bitsA, bitsB, meta);
    pipeline_kernel<<<NG, PT, 0, stream>>>(sa, sb, bitsA, bitsB, meta, msg);
    expand_kernel<<<18432, 256, 0, stream>>>(bitsA, bitsB, meta, out);
}